// Round 6
// baseline (577.501 us; speedup 1.0000x reference)
//
#include <hip/hip_runtime.h>
#include <hip/hip_bf16.h>
#include <hip/hip_fp16.h>

typedef __attribute__((ext_vector_type(8))) short short8;
typedef __attribute__((ext_vector_type(4))) float f32x4;

#define GLL(g, s) __builtin_amdgcn_global_load_lds(                        \
    (const __attribute__((address_space(1))) void*)(g),                    \
    (__attribute__((address_space(3))) void*)(s), 16, 0, 0)

__device__ __forceinline__ ushort f2bf(float f) {
    unsigned u = __float_as_uint(f);
    u += 0x7fffu + ((u >> 16) & 1u);
    return (ushort)(u >> 16);
}
__device__ __forceinline__ float bf2f(ushort h) {
    return __uint_as_float(((unsigned)h) << 16);
}
__device__ __forceinline__ float elu_f(float x) {
    return x > 0.0f ? x : expm1f(x);
}
__device__ __forceinline__ float lrelu(float x) {
    return x < 0.0f ? 0.2f * x : x;
}

// ---------------- CSR build ----------------
__global__ void hist_kernel(const int* __restrict__ ei, int* __restrict__ deg, int E, int n) {
    int total = E + n;
    for (int i = blockIdx.x * blockDim.x + threadIdx.x; i < total; i += gridDim.x * blockDim.x) {
        int d = (i < E) ? ei[E + i] : (i - E);
        atomicAdd(&deg[d], 1);
    }
}

__global__ __launch_bounds__(256) void partial_kernel(const int* __restrict__ deg, int* __restrict__ bsums, int n) {
    __shared__ int sm[256];
    int t = threadIdx.x;
    int idx = blockIdx.x * 256 + t;
    sm[t] = (idx < n) ? deg[idx] : 0;
    __syncthreads();
    #pragma unroll
    for (int off = 128; off > 0; off >>= 1) {
        if (t < off) sm[t] += sm[t + off];
        __syncthreads();
    }
    if (t == 0) bsums[blockIdx.x] = sm[0];
}

// lookback finalize: each block computes its own base from bsums (nb ~ 196, L2-hot)
__global__ __launch_bounds__(256) void finalize2_kernel(const int* __restrict__ deg, const int* __restrict__ bsums,
                                                        int* __restrict__ rowptr, int* __restrict__ cursor,
                                                        int n, int nb) {
    __shared__ int sm[256];
    __shared__ int sbase;
    int t = threadIdx.x, b = blockIdx.x;
    int part = 0;
    for (int i = t; i < b; i += 256) part += bsums[i];
    sm[t] = part;
    __syncthreads();
    #pragma unroll
    for (int off = 128; off > 0; off >>= 1) {
        if (t < off) sm[t] += sm[t + off];
        __syncthreads();
    }
    if (t == 0) sbase = sm[0];
    __syncthreads();
    int base = sbase;
    __syncthreads();
    int idx = b * 256 + t;
    int v = (idx < n) ? deg[idx] : 0;
    sm[t] = v;
    __syncthreads();
    #pragma unroll
    for (int off = 1; off < 256; off <<= 1) {
        int x = (t >= off) ? sm[t - off] : 0;
        __syncthreads();
        sm[t] += x;
        __syncthreads();
    }
    if (idx < n) {
        int ex = base + sm[t] - v;
        rowptr[idx] = ex;
        cursor[idx] = ex;
    }
    if (b == nb - 1 && t == 255) rowptr[n] = base + sm[255];
}

__global__ void scatter_kernel(const int* __restrict__ ei, int* __restrict__ cursor,
                               int* __restrict__ csr_src, int E, int n) {
    int total = E + n;
    for (int i = blockIdx.x * blockDim.x + threadIdx.x; i < total; i += gridDim.x * blockDim.x) {
        int s, d;
        if (i < E) { s = ei[i]; d = ei[E + i]; }
        else       { s = i - E; d = s; }
        int pos = atomicAdd(&cursor[d], 1);
        csr_src[pos] = s;
    }
}

// ---------------- unified pack: x (row-major A) + 3 weight mats -> fragment-major bf16 hi/lo
// A layout:  [(k>>3)*Mpad + r]*8 + (k&7)
// W layout:  [(k>>3)*Ncols + n]*8 + (k&7)
__global__ __launch_bounds__(256) void packall_kernel(const float* __restrict__ x,
                                                      const float* __restrict__ W1,
                                                      const float* __restrict__ W2,
                                                      const float* __restrict__ W3,
                                                      short* __restrict__ xh, short* __restrict__ xl,
                                                      short* __restrict__ w1h, short* __restrict__ w1l,
                                                      short* __restrict__ w2h, short* __restrict__ w2l,
                                                      short* __restrict__ w3h, short* __restrict__ w3l,
                                                      int M, int Mpad, int XB) {
    int b = blockIdx.x;
    int t = threadIdx.x;
    if (b < XB) {
        // x-pack: block handles 8 rows x 256 cols; thread = (row rr = t>>5, chunk cc = t&31)
        int r = b * 8 + (t >> 5);
        int cc = t & 31;
        if (r >= M) return;
        const float* src = x + (size_t)r * 256 + cc * 8;
        short8 hi, lo;
        #pragma unroll
        for (int j = 0; j < 8; ++j) {
            float v = src[j];
            ushort h = f2bf(v);
            hi[j] = (short)h;
            lo[j] = (short)f2bf(v - bf2f(h));
        }
        size_t o = ((size_t)cc * Mpad + r) * 8;
        *(short8*)(xh + o) = hi;
        *(short8*)(xl + o) = lo;
        return;
    }
    const float* W; short* hh; short* ll; int Ncols; int base;
    if (b < XB + 256)      { W = W1; hh = w1h; ll = w1l; Ncols = 256; base = XB; }
    else if (b < XB + 512) { W = W2; hh = w2h; ll = w2l; Ncols = 256; base = XB + 256; }
    else                   { W = W3; hh = w3h; ll = w3l; Ncols = 64;  base = XB + 512; }
    int idx = (b - base) * 256 + t;
    int k = idx / Ncols, n = idx - k * Ncols;
    float v = W[idx];
    ushort h = f2bf(v);
    ushort l = f2bf(v - bf2f(h));
    size_t o = ((size_t)(k >> 3) * Ncols + n) * 8 + (k & 7);
    hh[o] = (short)h;
    ll[o] = (short)l;
}

// ---------------- barrier-free all-packed MFMA GEMM ----------------
// C[M x NCOLS] = A[M x 256] @ W[256 x NCOLS] (+bias)
// 1 wave per block, tile 64 rows x FN*16 cols, BK=32, both operands bf16 hi/lo
// pre-packed fragment-major -> pure global_load_lds staging, zero conversion VALU,
// no __syncthreads; double-buffered with counted s_waitcnt vmcnt(N).
template<int FN, bool OUTHALF>
__global__ __launch_bounds__(64) void gemm_pk(const short* __restrict__ Aph, const short* __restrict__ Apl,
                                              const short* __restrict__ Bph, const short* __restrict__ Bpl,
                                              const float* __restrict__ bias, void* __restrict__ Cout,
                                              int M, int Mpad, int NCOLS) {
    __shared__ short Ah[2][4][64][8], Al[2][4][64][8];        // 16 KB
    __shared__ short Bh[2][4][FN * 16][8], Bl[2][4][FN * 16][8];
    const int lane = threadIdx.x;
    const int r0 = blockIdx.x * 64;
    const int c0 = blockIdx.y * FN * 16;
    const int c = lane >> 4;    // k-chunk of fragment
    const int rs = lane & 15;   // row-in-16 (A) / col-in-16 (B)

    auto issue = [&](int buf, int t) {
        #pragma unroll
        for (int q = 0; q < 4; ++q) {
            int kc = t * 4 + q;
            GLL(Aph + ((size_t)kc * Mpad + r0 + lane) * 8, &Ah[buf][q][0][0]);
            GLL(Apl + ((size_t)kc * Mpad + r0 + lane) * 8, &Al[buf][q][0][0]);
            #pragma unroll
            for (int hseg = 0; hseg < FN / 4; ++hseg) {
                GLL(Bph + ((size_t)kc * NCOLS + c0 + hseg * 64 + lane) * 8, &Bh[buf][q][hseg * 64][0]);
                GLL(Bpl + ((size_t)kc * NCOLS + c0 + hseg * 64 + lane) * 8, &Bl[buf][q][hseg * 64][0]);
            }
        }
    };

    f32x4 acc[4][FN];
    #pragma unroll
    for (int i = 0; i < 4; ++i)
        #pragma unroll
        for (int j = 0; j < FN; ++j)
            acc[i][j] = (f32x4){0.f, 0.f, 0.f, 0.f};

    issue(0, 0);
    issue(1, 1);

    #pragma unroll
    for (int t = 0; t < 8; ++t) {
        if (t < 7) {
            if constexpr (FN == 8) asm volatile("s_waitcnt vmcnt(24)" ::: "memory");
            else                   asm volatile("s_waitcnt vmcnt(16)" ::: "memory");
        } else {
            asm volatile("s_waitcnt vmcnt(0)" ::: "memory");
        }
        __builtin_amdgcn_sched_barrier(0);
        const int buf = t & 1;
        short8 ah[4], al[4];
        #pragma unroll
        for (int fm = 0; fm < 4; ++fm) {
            ah[fm] = *(const short8*)&Ah[buf][c][fm * 16 + rs][0];
            al[fm] = *(const short8*)&Al[buf][c][fm * 16 + rs][0];
        }
        short8 bh[FN], bl[FN];
        #pragma unroll
        for (int fn = 0; fn < FN; ++fn) {
            bh[fn] = *(const short8*)&Bh[buf][c][fn * 16 + rs][0];
            bl[fn] = *(const short8*)&Bl[buf][c][fn * 16 + rs][0];
        }
        // all ds_reads of this buffer issued; drain before overwriting it
        asm volatile("s_waitcnt lgkmcnt(0)" ::: "memory");
        __builtin_amdgcn_sched_barrier(0);
        if (t < 6) issue(buf, t + 2);
        #pragma unroll
        for (int fn = 0; fn < FN; ++fn) {
            #pragma unroll
            for (int fm = 0; fm < 4; ++fm) {
                acc[fm][fn] = __builtin_amdgcn_mfma_f32_16x16x32_bf16(ah[fm], bh[fn], acc[fm][fn], 0, 0, 0);
                acc[fm][fn] = __builtin_amdgcn_mfma_f32_16x16x32_bf16(ah[fm], bl[fn], acc[fm][fn], 0, 0, 0);
                acc[fm][fn] = __builtin_amdgcn_mfma_f32_16x16x32_bf16(al[fm], bh[fn], acc[fm][fn], 0, 0, 0);
            }
        }
    }

    // epilogue: C/D layout col = lane&15, row = (lane>>4)*4 + reg
    #pragma unroll
    for (int fn = 0; fn < FN; ++fn) {
        int col = c0 + fn * 16 + rs;
        float bv = bias ? bias[col] : 0.0f;
        #pragma unroll
        for (int fm = 0; fm < 4; ++fm) {
            #pragma unroll
            for (int g = 0; g < 4; ++g) {
                int r = r0 + fm * 16 + c * 4 + g;
                if (r < M) {
                    float v = acc[fm][fn][g] + bv;
                    if constexpr (OUTHALF)
                        ((__half*)Cout)[(size_t)r * NCOLS + col] = __float2half_rn(v);
                    else
                        ((float*)Cout)[(size_t)r * NCOLS + col] = v;
                }
            }
        }
    }
}

// ---------------- per-node attention halves from fp16 h (prescaled by log2e) -------
template<int HEADS>
__global__ __launch_bounds__(256) void sd_kernel(const __half* __restrict__ h, const float* __restrict__ a_src,
                                                 const float* __restrict__ a_dst, float* __restrict__ s_out,
                                                 float* __restrict__ d_out_, int nnodes) {
    int lane = threadIdx.x & 63;
    int node = blockIdx.x * 4 + (threadIdx.x >> 6);
    if (node >= nnodes) return;
    const __half2* hp = (const __half2*)(h + (size_t)node * 256 + lane * 4);
    float2 f01 = __half22float2(hp[0]);
    float2 f23 = __half22float2(hp[1]);
    float4 as = *(const float4*)&a_src[lane * 4];
    float4 ad = *(const float4*)&a_dst[lane * 4];
    float ps = f01.x * as.x + f01.y * as.y + f23.x * as.z + f23.y * as.w;
    float pd = f01.x * ad.x + f01.y * ad.y + f23.x * ad.z + f23.y * ad.w;
    const int GS = 64 / HEADS;
    #pragma unroll
    for (int off = 1; off < GS; off <<= 1) {
        ps += __shfl_xor(ps, off);
        pd += __shfl_xor(pd, off);
    }
    int g = lane / GS;
    int r = lane & (GS - 1);
    if (r == 0) s_out[(size_t)node * HEADS + g] = ps * 1.44269504f;
    if (r == 1) d_out_[(size_t)node * HEADS + g] = pd * 1.44269504f;
}

// ---------------- fused segment-softmax (shift-invariant, no max) + aggregate ------
// + bias + ELU; writes packed bf16 hi/lo (fragment-major) for the next GEMM.
// scores prescaled by log2e; w = exp2(v - 30): overflow needs v' > 158 (impossible),
// self-loop bounds den away from 0.
template<int HEADS>
__global__ __launch_bounds__(256) void agg_kernel(const int* __restrict__ rowptr, const int* __restrict__ csr_src,
                                                  const __half* __restrict__ h, const float* __restrict__ s_att,
                                                  const float* __restrict__ d_att, const float* __restrict__ bias,
                                                  short* __restrict__ outh, short* __restrict__ outl,
                                                  int nnodes, int Mpad) {
    int lane = threadIdx.x & 63;
    int node = blockIdx.x * 4 + (threadIdx.x >> 6);
    if (node >= nnodes) return;
    const int hh = (HEADS == 8) ? (lane >> 3) : 0;
    const int cbase = lane * 4;
    const int begin = rowptr[node], end = rowptr[node + 1];
    const float dl = d_att[(size_t)node * HEADS + hh];
    float den = 0.f;
    float ax = 0.f, ay = 0.f, az = 0.f, aw = 0.f;
    int i = begin;
    for (; i + 4 <= end; i += 4) {
        int s0 = csr_src[i], s1 = csr_src[i + 1], s2 = csr_src[i + 2], s3 = csr_src[i + 3];
        uint2 u0 = *(const uint2*)(h + (size_t)s0 * 256 + cbase);
        uint2 u1 = *(const uint2*)(h + (size_t)s1 * 256 + cbase);
        uint2 u2 = *(const uint2*)(h + (size_t)s2 * 256 + cbase);
        uint2 u3 = *(const uint2*)(h + (size_t)s3 * 256 + cbase);
        float w0 = exp2f(lrelu(s_att[(size_t)s0 * HEADS + hh] + dl) - 30.0f);
        float w1 = exp2f(lrelu(s_att[(size_t)s1 * HEADS + hh] + dl) - 30.0f);
        float w2 = exp2f(lrelu(s_att[(size_t)s2 * HEADS + hh] + dl) - 30.0f);
        float w3 = exp2f(lrelu(s_att[(size_t)s3 * HEADS + hh] + dl) - 30.0f);
        den += (w0 + w1) + (w2 + w3);
        float2 f0a = __half22float2(*(const __half2*)&u0.x), f0b = __half22float2(*(const __half2*)&u0.y);
        float2 f1a = __half22float2(*(const __half2*)&u1.x), f1b = __half22float2(*(const __half2*)&u1.y);
        float2 f2a = __half22float2(*(const __half2*)&u2.x), f2b = __half22float2(*(const __half2*)&u2.y);
        float2 f3a = __half22float2(*(const __half2*)&u3.x), f3b = __half22float2(*(const __half2*)&u3.y);
        ax += w0 * f0a.x + w1 * f1a.x + w2 * f2a.x + w3 * f3a.x;
        ay += w0 * f0a.y + w1 * f1a.y + w2 * f2a.y + w3 * f3a.y;
        az += w0 * f0b.x + w1 * f1b.x + w2 * f2b.x + w3 * f3b.x;
        aw += w0 * f0b.y + w1 * f1b.y + w2 * f2b.y + w3 * f3b.y;
    }
    for (; i < end; ++i) {
        int s0 = csr_src[i];
        uint2 u0 = *(const uint2*)(h + (size_t)s0 * 256 + cbase);
        float w0 = exp2f(lrelu(s_att[(size_t)s0 * HEADS + hh] + dl) - 30.0f);
        den += w0;
        float2 f0a = __half22float2(*(const __half2*)&u0.x), f0b = __half22float2(*(const __half2*)&u0.y);
        ax += w0 * f0a.x;
        ay += w0 * f0a.y;
        az += w0 * f0b.x;
        aw += w0 * f0b.y;
    }
    float inv = 1.0f / den;
    float4 bv = *(const float4*)&bias[cbase];
    float r0 = elu_f(ax * inv + bv.x);
    float r1 = elu_f(ay * inv + bv.y);
    float r2 = elu_f(az * inv + bv.z);
    float r3 = elu_f(aw * inv + bv.w);
    // packed write: chunk = lane>>1, sub-offset = (lane&1)*4
    ushort h0 = f2bf(r0), h1 = f2bf(r1), h2 = f2bf(r2), h3 = f2bf(r3);
    ushort l0 = f2bf(r0 - bf2f(h0)), l1 = f2bf(r1 - bf2f(h1));
    ushort l2 = f2bf(r2 - bf2f(h2)), l3 = f2bf(r3 - bf2f(h3));
    size_t o = ((size_t)(lane >> 1) * Mpad + node) * 8 + (lane & 1) * 4;
    uint2 hv, lv;
    hv.x = (unsigned)h0 | ((unsigned)h1 << 16);
    hv.y = (unsigned)h2 | ((unsigned)h3 << 16);
    lv.x = (unsigned)l0 | ((unsigned)l1 << 16);
    lv.y = (unsigned)l2 | ((unsigned)l3 << 16);
    *(uint2*)(outh + o) = hv;
    *(uint2*)(outl + o) = lv;
}

extern "C" void kernel_launch(void* const* d_in, const int* in_sizes, int n_in,
                              void* d_out, int out_size, void* d_ws, size_t ws_size,
                              hipStream_t stream) {
    const float* x      = (const float*)d_in[0];
    const int*   ei     = (const int*)d_in[1];
    const float* W1     = (const float*)d_in[2];
    const float* a_src1 = (const float*)d_in[3];
    const float* a_dst1 = (const float*)d_in[4];
    const float* b1     = (const float*)d_in[5];
    const float* W2     = (const float*)d_in[6];
    const float* a_src2 = (const float*)d_in[7];
    const float* a_dst2 = (const float*)d_in[8];
    const float* b2     = (const float*)d_in[9];
    const float* Wlin   = (const float*)d_in[10];
    const float* blin   = (const float*)d_in[11];
    float* out = (float*)d_out;

    const int N = in_sizes[0] / 256;   // 50000 nodes
    const int E = in_sizes[1] / 2;     // 800000 edges
    const int ET = E + N;
    const int NB = (N + 255) / 256;
    const int Mpad = ((N + 63) / 64) * 64;   // 50048

    char* p = (char*)d_ws;
    auto alloc = [&](size_t bytes) {
        void* r = (void*)p;
        p += (bytes + 255) & ~size_t(255);
        return r;
    };
    __half* bufH  = (__half*)alloc((size_t)N * 256 * 2);       // fp16 h (gemm1/2 out)
    short* Aph    = (short*)alloc((size_t)Mpad * 256 * 2);     // packed A hi (x / agg1 / agg2)
    short* Apl    = (short*)alloc((size_t)Mpad * 256 * 2);     // packed A lo
    float* s1     = (float*)alloc((size_t)N * 8 * 4);
    float* d1     = (float*)alloc((size_t)N * 8 * 4);
    float* s2     = (float*)alloc((size_t)N * 4);
    float* d2     = (float*)alloc((size_t)N * 4);
    int*   deg    = (int*)alloc((size_t)N * 4);
    int*   cursor = (int*)alloc((size_t)N * 4);
    int*   rowptr = (int*)alloc((size_t)(N + 1) * 4);
    int*   csr    = (int*)alloc((size_t)ET * 4);
    int*   bsums  = (int*)alloc((size_t)NB * 4);
    short* W1h    = (short*)alloc((size_t)256 * 256 * 2);
    short* W1l    = (short*)alloc((size_t)256 * 256 * 2);
    short* W2h    = (short*)alloc((size_t)256 * 256 * 2);
    short* W2l    = (short*)alloc((size_t)256 * 256 * 2);
    short* W3h    = (short*)alloc((size_t)256 * 64 * 2);
    short* W3l    = (short*)alloc((size_t)256 * 64 * 2);

    // ---- CSR build ----
    hipMemsetAsync(deg, 0, (size_t)N * 4, stream);
    hist_kernel<<<(ET + 255) / 256, 256, 0, stream>>>(ei, deg, E, N);
    partial_kernel<<<NB, 256, 0, stream>>>(deg, bsums, N);
    finalize2_kernel<<<NB, 256, 0, stream>>>(deg, bsums, rowptr, cursor, N, NB);
    scatter_kernel<<<(ET + 255) / 256, 256, 0, stream>>>(ei, cursor, csr, E, N);

    // ---- unified pack (x + 3 weights) ----
    const int XB = (N + 7) / 8;   // 6250
    packall_kernel<<<XB + 512 + 64, 256, 0, stream>>>(x, W1, W2, Wlin,
                                                      Aph, Apl, W1h, W1l, W2h, W2l, W3h, W3l,
                                                      N, Mpad, XB);

    const int gBlocks = (N + 63) / 64;
    const int nodeBlocks = (N + 3) / 4;

    // ---- layer 1 ----
    gemm_pk<8, true><<<dim3(gBlocks, 2), 64, 0, stream>>>(Aph, Apl, W1h, W1l, nullptr, bufH, N, Mpad, 256);
    sd_kernel<8><<<nodeBlocks, 256, 0, stream>>>(bufH, a_src1, a_dst1, s1, d1, N);
    agg_kernel<8><<<nodeBlocks, 256, 0, stream>>>(rowptr, csr, bufH, s1, d1, b1, Aph, Apl, N, Mpad);

    // ---- layer 2 ----
    gemm_pk<8, true><<<dim3(gBlocks, 2), 64, 0, stream>>>(Aph, Apl, W2h, W2l, nullptr, bufH, N, Mpad, 256);
    sd_kernel<1><<<nodeBlocks, 256, 0, stream>>>(bufH, a_src2, a_dst2, s2, d2, N);
    agg_kernel<1><<<nodeBlocks, 256, 0, stream>>>(rowptr, csr, bufH, s2, d2, b2, Aph, Apl, N, Mpad);

    // ---- final linear ----
    gemm_pk<4, false><<<dim3(gBlocks, 1), 64, 0, stream>>>(Aph, Apl, W3h, W3l, blin, out, N, Mpad, 64);
}

// Round 7
// 475.069 us; speedup vs baseline: 1.2156x; 1.2156x over previous
//
#include <hip/hip_runtime.h>
#include <hip/hip_bf16.h>
#include <hip/hip_fp16.h>

typedef __attribute__((ext_vector_type(8))) _Float16 half8;
typedef __attribute__((ext_vector_type(4))) float f32x4;

#define GLL(g, s) __builtin_amdgcn_global_load_lds(                        \
    (const __attribute__((address_space(1))) void*)(g),                    \
    (__attribute__((address_space(3))) void*)(s), 16, 0, 0)

__device__ __forceinline__ float elu_f(float x) {
    return x > 0.0f ? x : expm1f(x);
}
__device__ __forceinline__ float lrelu(float x) {
    return x < 0.0f ? 0.2f * x : x;
}

// ---------------- CSR build ----------------
__global__ void hist_kernel(const int* __restrict__ ei, int* __restrict__ deg, int E, int n) {
    int total = E + n;
    for (int i = blockIdx.x * blockDim.x + threadIdx.x; i < total; i += gridDim.x * blockDim.x) {
        int d = (i < E) ? ei[E + i] : (i - E);
        atomicAdd(&deg[d], 1);
    }
}

__global__ __launch_bounds__(256) void partial_kernel(const int* __restrict__ deg, int* __restrict__ bsums, int n) {
    __shared__ int sm[256];
    int t = threadIdx.x;
    int idx = blockIdx.x * 256 + t;
    sm[t] = (idx < n) ? deg[idx] : 0;
    __syncthreads();
    #pragma unroll
    for (int off = 128; off > 0; off >>= 1) {
        if (t < off) sm[t] += sm[t + off];
        __syncthreads();
    }
    if (t == 0) bsums[blockIdx.x] = sm[0];
}

// lookback finalize: each block computes its own base from bsums (nb ~ 196, L2-hot)
__global__ __launch_bounds__(256) void finalize2_kernel(const int* __restrict__ deg, const int* __restrict__ bsums,
                                                        int* __restrict__ rowptr, int* __restrict__ cursor,
                                                        int n, int nb) {
    __shared__ int sm[256];
    __shared__ int sbase;
    int t = threadIdx.x, b = blockIdx.x;
    int part = 0;
    for (int i = t; i < b; i += 256) part += bsums[i];
    sm[t] = part;
    __syncthreads();
    #pragma unroll
    for (int off = 128; off > 0; off >>= 1) {
        if (t < off) sm[t] += sm[t + off];
        __syncthreads();
    }
    if (t == 0) sbase = sm[0];
    __syncthreads();
    int base = sbase;
    __syncthreads();
    int idx = b * 256 + t;
    int v = (idx < n) ? deg[idx] : 0;
    sm[t] = v;
    __syncthreads();
    #pragma unroll
    for (int off = 1; off < 256; off <<= 1) {
        int x = (t >= off) ? sm[t - off] : 0;
        __syncthreads();
        sm[t] += x;
        __syncthreads();
    }
    if (idx < n) {
        int ex = base + sm[t] - v;
        rowptr[idx] = ex;
        cursor[idx] = ex;
    }
    if (b == nb - 1 && t == 255) rowptr[n] = base + sm[255];
}

__global__ void scatter_kernel(const int* __restrict__ ei, int* __restrict__ cursor,
                               int* __restrict__ csr_src, int E, int n) {
    int total = E + n;
    for (int i = blockIdx.x * blockDim.x + threadIdx.x; i < total; i += gridDim.x * blockDim.x) {
        int s, d;
        if (i < E) { s = ei[i]; d = ei[E + i]; }
        else       { s = i - E; d = s; }
        int pos = atomicAdd(&cursor[d], 1);
        csr_src[pos] = s;
    }
}

// ---------------- pack: x -> fp16 node-major; W1/W2/W3 -> fp16 fragment-major ------
// W layout: [(k>>3)*Ncols + n]*8 + (k&7)
__global__ __launch_bounds__(256) void packall_kernel(const float* __restrict__ x,
                                                      const float* __restrict__ W1,
                                                      const float* __restrict__ W2,
                                                      const float* __restrict__ W3,
                                                      _Float16* __restrict__ xp,
                                                      _Float16* __restrict__ w1p,
                                                      _Float16* __restrict__ w2p,
                                                      _Float16* __restrict__ w3p,
                                                      int Mtot, int XB) {
    int b = blockIdx.x;
    int t = threadIdx.x;
    if (b < XB) {
        // x: elementwise fp32 -> fp16, 8 elems/thread, contiguous
        size_t idx = ((size_t)b * 256 + t) * 8;
        if (idx >= (size_t)Mtot * 256) return;
        const float* src = x + idx;
        half8 v;
        #pragma unroll
        for (int j = 0; j < 8; ++j) v[j] = (_Float16)src[j];
        *(half8*)(xp + idx) = v;
        return;
    }
    const float* W; _Float16* wp; int Ncols; int base;
    if (b < XB + 256)      { W = W1; wp = w1p; Ncols = 256; base = XB; }
    else if (b < XB + 512) { W = W2; wp = w2p; Ncols = 256; base = XB + 256; }
    else                   { W = W3; wp = w3p; Ncols = 64;  base = XB + 512; }
    int idx = (b - base) * 256 + t;
    int k = idx / Ncols, n = idx - k * Ncols;
    size_t o = ((size_t)(k >> 3) * Ncols + n) * 8 + (k & 7);
    wp[o] = (_Float16)W[idx];
}

// ---------------- barrier-free fp16 MFMA GEMM ----------------
// C[M x NCOLS] = A[M x 256] @ W[256 x NCOLS] (+bias)
// A: fp16 NODE-MAJOR [row][256] -> staged via GLL per-lane gather (lane = row).
// B: fp16 fragment-major packed -> linear GLL.
// 1 wave/block, tile 64 x FN*16, BK=32, 24KB LDS (FN=8) -> 6 blocks/CU,
// no __syncthreads, double-buffered, counted s_waitcnt vmcnt.
template<int FN, bool OUTHALF>
__global__ __launch_bounds__(64) void gemm_pk(const _Float16* __restrict__ Apk,
                                              const _Float16* __restrict__ Bpk,
                                              const float* __restrict__ bias, void* __restrict__ Cout,
                                              int M, int NCOLS) {
    __shared__ _Float16 Ah[2][4][64][8];        // 8 KB
    __shared__ _Float16 Bh[2][4][FN * 16][8];   // 16 KB (FN=8) / 8 KB (FN=4)
    const int lane = threadIdx.x;
    const int r0 = blockIdx.x * 64;
    const int c0 = blockIdx.y * FN * 16;
    const int c = lane >> 4;    // k-chunk of fragment
    const int rs = lane & 15;   // row-in-16 (A) / col-in-16 (B)

    auto issue = [&](int buf, int t) {
        #pragma unroll
        for (int q = 0; q < 4; ++q) {
            int kc = t * 4 + q;
            // per-lane global source: lane l -> row r0+l, 16B fragment
            GLL(Apk + (size_t)(r0 + lane) * 256 + kc * 8, &Ah[buf][q][0][0]);
            #pragma unroll
            for (int hs = 0; hs < FN / 4; ++hs)
                GLL(Bpk + ((size_t)kc * NCOLS + c0 + hs * 64 + lane) * 8, &Bh[buf][q][hs * 64][0]);
        }
    };

    f32x4 acc[4][FN];
    #pragma unroll
    for (int i = 0; i < 4; ++i)
        #pragma unroll
        for (int j = 0; j < FN; ++j)
            acc[i][j] = (f32x4){0.f, 0.f, 0.f, 0.f};

    issue(0, 0);
    issue(1, 1);

    #pragma unroll
    for (int t = 0; t < 8; ++t) {
        // one batch = 4*(1 + FN/4) vmem ops; keep next batch in flight
        if (t < 7) {
            if constexpr (FN == 8) asm volatile("s_waitcnt vmcnt(12)" ::: "memory");
            else                   asm volatile("s_waitcnt vmcnt(8)" ::: "memory");
        } else {
            asm volatile("s_waitcnt vmcnt(0)" ::: "memory");
        }
        __builtin_amdgcn_sched_barrier(0);
        const int buf = t & 1;
        half8 ah[4];
        #pragma unroll
        for (int fm = 0; fm < 4; ++fm)
            ah[fm] = *(const half8*)&Ah[buf][c][fm * 16 + rs][0];
        half8 bh[FN];
        #pragma unroll
        for (int fn = 0; fn < FN; ++fn)
            bh[fn] = *(const half8*)&Bh[buf][c][fn * 16 + rs][0];
        // drain ds_reads into VGPRs before overwriting this buffer
        asm volatile("s_waitcnt lgkmcnt(0)" ::: "memory");
        __builtin_amdgcn_sched_barrier(0);
        if (t < 6) issue(buf, t + 2);
        #pragma unroll
        for (int fn = 0; fn < FN; ++fn)
            #pragma unroll
            for (int fm = 0; fm < 4; ++fm)
                acc[fm][fn] = __builtin_amdgcn_mfma_f32_16x16x32_f16(ah[fm], bh[fn], acc[fm][fn], 0, 0, 0);
    }

    // epilogue: C/D layout col = lane&15, row = (lane>>4)*4 + reg
    #pragma unroll
    for (int fn = 0; fn < FN; ++fn) {
        int col = c0 + fn * 16 + rs;
        float bv = bias ? bias[col] : 0.0f;
        #pragma unroll
        for (int fm = 0; fm < 4; ++fm) {
            #pragma unroll
            for (int g = 0; g < 4; ++g) {
                int r = r0 + fm * 16 + c * 4 + g;
                if (r < M) {
                    float v = acc[fm][fn][g] + bv;
                    if constexpr (OUTHALF)
                        ((__half*)Cout)[(size_t)r * NCOLS + col] = __float2half_rn(v);
                    else
                        ((float*)Cout)[(size_t)r * NCOLS + col] = v;
                }
            }
        }
    }
}

// ---------------- per-node attention halves from fp16 h (prescaled by log2e) -------
template<int HEADS>
__global__ __launch_bounds__(256) void sd_kernel(const __half* __restrict__ h, const float* __restrict__ a_src,
                                                 const float* __restrict__ a_dst, float* __restrict__ s_out,
                                                 float* __restrict__ d_out_, int nnodes) {
    int lane = threadIdx.x & 63;
    int node = blockIdx.x * 4 + (threadIdx.x >> 6);
    if (node >= nnodes) return;
    const __half2* hp = (const __half2*)(h + (size_t)node * 256 + lane * 4);
    float2 f01 = __half22float2(hp[0]);
    float2 f23 = __half22float2(hp[1]);
    float4 as = *(const float4*)&a_src[lane * 4];
    float4 ad = *(const float4*)&a_dst[lane * 4];
    float ps = f01.x * as.x + f01.y * as.y + f23.x * as.z + f23.y * as.w;
    float pd = f01.x * ad.x + f01.y * ad.y + f23.x * ad.z + f23.y * ad.w;
    const int GS = 64 / HEADS;
    #pragma unroll
    for (int off = 1; off < GS; off <<= 1) {
        ps += __shfl_xor(ps, off);
        pd += __shfl_xor(pd, off);
    }
    int g = lane / GS;
    int r = lane & (GS - 1);
    if (r == 0) s_out[(size_t)node * HEADS + g] = ps * 1.44269504f;
    if (r == 1) d_out_[(size_t)node * HEADS + g] = pd * 1.44269504f;
}

// ---------------- fused segment-softmax (shift-invariant exp2) + aggregate ---------
// + bias + ELU; writes fp16 node-major (contiguous) for the next GEMM's A.
template<int HEADS>
__global__ __launch_bounds__(256) void agg_kernel(const int* __restrict__ rowptr, const int* __restrict__ csr_src,
                                                  const __half* __restrict__ h, const float* __restrict__ s_att,
                                                  const float* __restrict__ d_att, const float* __restrict__ bias,
                                                  _Float16* __restrict__ outH, int nnodes) {
    int lane = threadIdx.x & 63;
    int node = blockIdx.x * 4 + (threadIdx.x >> 6);
    if (node >= nnodes) return;
    const int hh = (HEADS == 8) ? (lane >> 3) : 0;
    const int cbase = lane * 4;
    const int begin = rowptr[node], end = rowptr[node + 1];
    const float dl = d_att[(size_t)node * HEADS + hh];
    float den = 0.f;
    float ax = 0.f, ay = 0.f, az = 0.f, aw = 0.f;
    int i = begin;
    for (; i + 4 <= end; i += 4) {
        int s0 = csr_src[i], s1 = csr_src[i + 1], s2 = csr_src[i + 2], s3 = csr_src[i + 3];
        uint2 u0 = *(const uint2*)(h + (size_t)s0 * 256 + cbase);
        uint2 u1 = *(const uint2*)(h + (size_t)s1 * 256 + cbase);
        uint2 u2 = *(const uint2*)(h + (size_t)s2 * 256 + cbase);
        uint2 u3 = *(const uint2*)(h + (size_t)s3 * 256 + cbase);
        float w0 = exp2f(lrelu(s_att[(size_t)s0 * HEADS + hh] + dl) - 30.0f);
        float w1 = exp2f(lrelu(s_att[(size_t)s1 * HEADS + hh] + dl) - 30.0f);
        float w2 = exp2f(lrelu(s_att[(size_t)s2 * HEADS + hh] + dl) - 30.0f);
        float w3 = exp2f(lrelu(s_att[(size_t)s3 * HEADS + hh] + dl) - 30.0f);
        den += (w0 + w1) + (w2 + w3);
        float2 f0a = __half22float2(*(const __half2*)&u0.x), f0b = __half22float2(*(const __half2*)&u0.y);
        float2 f1a = __half22float2(*(const __half2*)&u1.x), f1b = __half22float2(*(const __half2*)&u1.y);
        float2 f2a = __half22float2(*(const __half2*)&u2.x), f2b = __half22float2(*(const __half2*)&u2.y);
        float2 f3a = __half22float2(*(const __half2*)&u3.x), f3b = __half22float2(*(const __half2*)&u3.y);
        ax += w0 * f0a.x + w1 * f1a.x + w2 * f2a.x + w3 * f3a.x;
        ay += w0 * f0a.y + w1 * f1a.y + w2 * f2a.y + w3 * f3a.y;
        az += w0 * f0b.x + w1 * f1b.x + w2 * f2b.x + w3 * f3b.x;
        aw += w0 * f0b.y + w1 * f1b.y + w2 * f2b.y + w3 * f3b.y;
    }
    for (; i < end; ++i) {
        int s0 = csr_src[i];
        uint2 u0 = *(const uint2*)(h + (size_t)s0 * 256 + cbase);
        float w0 = exp2f(lrelu(s_att[(size_t)s0 * HEADS + hh] + dl) - 30.0f);
        den += w0;
        float2 f0a = __half22float2(*(const __half2*)&u0.x), f0b = __half22float2(*(const __half2*)&u0.y);
        ax += w0 * f0a.x;
        ay += w0 * f0a.y;
        az += w0 * f0b.x;
        aw += w0 * f0b.y;
    }
    float inv = 1.0f / den;
    float4 bv = *(const float4*)&bias[cbase];
    float r0 = elu_f(ax * inv + bv.x);
    float r1 = elu_f(ay * inv + bv.y);
    float r2 = elu_f(az * inv + bv.z);
    float r3 = elu_f(aw * inv + bv.w);
    __half2 o01 = __floats2half2_rn(r0, r1);
    __half2 o23 = __floats2half2_rn(r2, r3);
    uint2 wv;
    wv.x = *(unsigned*)&o01;
    wv.y = *(unsigned*)&o23;
    *(uint2*)(outH + (size_t)node * 256 + cbase) = wv;  // contiguous 512B/wave
}

extern "C" void kernel_launch(void* const* d_in, const int* in_sizes, int n_in,
                              void* d_out, int out_size, void* d_ws, size_t ws_size,
                              hipStream_t stream) {
    const float* x      = (const float*)d_in[0];
    const int*   ei     = (const int*)d_in[1];
    const float* W1     = (const float*)d_in[2];
    const float* a_src1 = (const float*)d_in[3];
    const float* a_dst1 = (const float*)d_in[4];
    const float* b1     = (const float*)d_in[5];
    const float* W2     = (const float*)d_in[6];
    const float* a_src2 = (const float*)d_in[7];
    const float* a_dst2 = (const float*)d_in[8];
    const float* b2     = (const float*)d_in[9];
    const float* Wlin   = (const float*)d_in[10];
    const float* blin   = (const float*)d_in[11];
    float* out = (float*)d_out;

    const int N = in_sizes[0] / 256;   // 50000 nodes
    const int E = in_sizes[1] / 2;     // 800000 edges
    const int ET = E + N;
    const int NB = (N + 255) / 256;
    const int Mpad = ((N + 63) / 64) * 64;   // 50048

    char* p = (char*)d_ws;
    auto alloc = [&](size_t bytes) {
        void* r = (void*)p;
        p += (bytes + 255) & ~size_t(255);
        return r;
    };
    __half*    bufH = (__half*)alloc((size_t)Mpad * 256 * 2);    // h (gemm out, fp16)
    _Float16*  Apk  = (_Float16*)alloc((size_t)Mpad * 256 * 2);  // A fp16 node-major (x / agg1 / agg2)
    float* s1     = (float*)alloc((size_t)N * 8 * 4);
    float* d1     = (float*)alloc((size_t)N * 8 * 4);
    float* s2     = (float*)alloc((size_t)N * 4);
    float* d2     = (float*)alloc((size_t)N * 4);
    int*   deg    = (int*)alloc((size_t)N * 4);
    int*   cursor = (int*)alloc((size_t)N * 4);
    int*   rowptr = (int*)alloc((size_t)(N + 1) * 4);
    int*   csr    = (int*)alloc((size_t)ET * 4);
    int*   bsums  = (int*)alloc((size_t)NB * 4);
    _Float16* W1p = (_Float16*)alloc((size_t)256 * 256 * 2);
    _Float16* W2p = (_Float16*)alloc((size_t)256 * 256 * 2);
    _Float16* W3p = (_Float16*)alloc((size_t)256 * 64 * 2);

    // ---- CSR build ----
    hipMemsetAsync(deg, 0, (size_t)N * 4, stream);
    hist_kernel<<<(ET + 255) / 256, 256, 0, stream>>>(ei, deg, E, N);
    partial_kernel<<<NB, 256, 0, stream>>>(deg, bsums, N);
    finalize2_kernel<<<NB, 256, 0, stream>>>(deg, bsums, rowptr, cursor, N, NB);
    scatter_kernel<<<(ET + 255) / 256, 256, 0, stream>>>(ei, cursor, csr, E, N);

    // ---- pack (x fp16 + 3 weights fragment-major fp16) ----
    const int XB = (N * 256 + 2047) / 2048;   // 6250
    packall_kernel<<<XB + 512 + 64, 256, 0, stream>>>(x, W1, W2, Wlin,
                                                      Apk, W1p, W2p, W3p, N, XB);

    const int gBlocks = (N + 63) / 64;
    const int nodeBlocks = (N + 3) / 4;

    // ---- layer 1 ----
    gemm_pk<8, true><<<dim3(gBlocks, 2), 64, 0, stream>>>(Apk, W1p, nullptr, bufH, N, 256);
    sd_kernel<8><<<nodeBlocks, 256, 0, stream>>>(bufH, a_src1, a_dst1, s1, d1, N);
    agg_kernel<8><<<nodeBlocks, 256, 0, stream>>>(rowptr, csr, bufH, s1, d1, b1, Apk, N);

    // ---- layer 2 ----
    gemm_pk<8, true><<<dim3(gBlocks, 2), 64, 0, stream>>>(Apk, W2p, nullptr, bufH, N, 256);
    sd_kernel<1><<<nodeBlocks, 256, 0, stream>>>(bufH, a_src2, a_dst2, s2, d2, N);
    agg_kernel<1><<<nodeBlocks, 256, 0, stream>>>(rowptr, csr, bufH, s2, d2, b2, Apk, N);

    // ---- final linear ----
    gemm_pk<4, false><<<dim3(gBlocks, 1), 64, 0, stream>>>(Apk, W3p, blin, out, N, 64);
}